// Round 9
// baseline (118.651 us; speedup 1.0000x reference)
//
#include <hip/hip_runtime.h>
#include <hip/hip_bf16.h>

#define Bb 512
#define Tt 512
#define Kk 64
#define START_TAG 62
#define STOP_TAG 63
#define LN2F 0.69314718055994530942f
#define LOG2E 1.44269504088896340736f

typedef __attribute__((ext_vector_type(8))) short bf16x8;  // 8 bf16 in 4 VGPRs
typedef __attribute__((ext_vector_type(4))) float f32x4;   // MFMA C/D

__device__ inline short f2bf(float x) {
    __hip_bfloat16 h = __float2bfloat16(x);
    short s; __builtin_memcpy(&s, &h, 2); return s;
}
// pack 2 f32 -> 2 bf16 in one instruction
__device__ inline unsigned cvtpk(float lo, float hi) {
    unsigned r;
    asm("v_cvt_pk_bf16_f32 %0, %1, %2" : "=v"(r) : "v"(lo), "v"(hi));
    return r;
}

// One sequence per 64-lane wave; alpha recursion as MFMA matvec in exp-space.
// Layout (HW-verified r4-r8, absmax 0.0): tag tau(c,r)=32c+16*(r>=4)+4g+(r&3)
// on both A and B sides; D tile i reg r = tag 16i+4g+r -> D feeds next B with
// register moves only.
// Round-9 changes (three null scheduling rounds -> attack the two survivors):
//  * UNCHAINED MFMAs: 8 independent MFMA(.,.,0) + 4 vector adds, instead of
//    4 SrcC-chained pairs. Removes any same-accumulator back-to-back hazard
//    from the serial chain (1 wave/SIMD exposes every cycle of it).
//  * 4-bank rotating LDS frl[4][64] (write bank t&3 = fr(t+4); read banks
//    (t+2)&3,(t+3)&3): reads/writes within an iteration never alias -> NO
//    wave_barrier in the loop at all; ordering is carried by exact LDS
//    address disambiguation with >=2 iterations of slack on every dep.
// Rescale queue (kq0/kq1/kemb in-flight accounting, r7-validated) unchanged:
// write->consume distance is still 4 steps.
__global__ __launch_bounds__(64, 1) void crf_forward_mfma(
    const float* __restrict__ feats,        // (B,T,K)
    const float* __restrict__ transitions,  // (K,K), trans[i,j] = score j->i
    const int* __restrict__ lengths,        // (B,)
    float* __restrict__ fwd_out)            // (B,)
{
    const int b   = blockIdx.x;
    const int l   = threadIdx.x;
    const int row = l & 15;   // A row / D col
    const int g   = l >> 4;   // k-group

    // fr banks: fr(s) lives in bank s&3, natural layout (lane = tag).
    __shared__ __align__(16) float frl[4][Kk];

    // A fragments: A[i][c] slot r = exp(trans[16i+row][tau(c,r)])
    bf16x8 A00, A01, A10, A11, A20, A21, A30, A31, S0, S1;
#define MKA(Av, i, c) {                                                       \
    const float* p = transitions + (16*(i)+row)*Kk + 32*(c) + 4*g;            \
    float4 lo = *(const float4*)p; float4 hi = *(const float4*)(p + 16);      \
    Av[0]=f2bf(__expf(lo.x)); Av[1]=f2bf(__expf(lo.y));                       \
    Av[2]=f2bf(__expf(lo.z)); Av[3]=f2bf(__expf(lo.w));                       \
    Av[4]=f2bf(__expf(hi.x)); Av[5]=f2bf(__expf(hi.y));                       \
    Av[6]=f2bf(__expf(hi.z)); Av[7]=f2bf(__expf(hi.w)); }
    MKA(A00,0,0) MKA(A01,0,1) MKA(A10,1,0) MKA(A11,1,1)
    MKA(A20,2,0) MKA(A21,2,1) MKA(A30,3,0) MKA(A31,3,1)
#undef MKA
    // Terminal fragments: row 0 = exp(trans[STOP][tau]), rows 1..15 = 0
#define MKS(Av, c) {                                                          \
    const float* p = transitions + STOP_TAG*Kk + 32*(c) + 4*g;                \
    float4 lo = *(const float4*)p; float4 hi = *(const float4*)(p + 16);      \
    const bool z = (row == 0);                                                \
    Av[0]=z?f2bf(__expf(lo.x)):(short)0; Av[1]=z?f2bf(__expf(lo.y)):(short)0; \
    Av[2]=z?f2bf(__expf(lo.z)):(short)0; Av[3]=z?f2bf(__expf(lo.w)):(short)0; \
    Av[4]=z?f2bf(__expf(hi.x)):(short)0; Av[5]=z?f2bf(__expf(hi.y)):(short)0; \
    Av[6]=z?f2bf(__expf(hi.z)):(short)0; Av[7]=z?f2bf(__expf(hi.w)):(short)0; }
    MKS(S0,0) MKS(S1,1)
#undef MKS

    const int len = lengths[b];
    const float* fb = feats + (size_t)b * Tt * Kk + l;  // natural: lane = tag

    // alpha0: 1 at START=62 -> B1 slot 6, g=3
    bf16x8 B0 = {}; bf16x8 B1 = {};
    if (g == 3) B1[6] = (short)0x3F80;  // bf16(1.0)

    // ---- prologue: banks 0..3 = fr(0..3); FA=F(0), FB=F(1) ----
    frl[0][l] = __builtin_amdgcn_exp2f(fb[0]      * LOG2E);
    frl[1][l] = __builtin_amdgcn_exp2f(fb[Kk]     * LOG2E);
    frl[2][l] = __builtin_amdgcn_exp2f(fb[2 * Kk] * LOG2E);
    frl[3][l] = __builtin_amdgcn_exp2f(fb[3 * Kk] * LOG2E);
    __builtin_amdgcn_wave_barrier();   // prologue only; loop has no fences
    f32x4 FA0, FA1, FA2, FA3, FB0, FB1, FB2, FB3;
    {
        const float* p0 = &frl[0][4 * g];
        const float* p1 = &frl[1][4 * g];
        FA0 = *(const f32x4*)(p0);      FA1 = *(const f32x4*)(p0 + 16);
        FA2 = *(const f32x4*)(p0 + 32); FA3 = *(const f32x4*)(p0 + 48);
        FB0 = *(const f32x4*)(p1);      FB1 = *(const f32x4*)(p1 + 16);
        FB2 = *(const f32x4*)(p1 + 32); FB3 = *(const f32x4*)(p1 + 48);
    }

    // emit ring, 4 deep: er0..er3 = rows t+4..t+7 (rows always allocated)
    float er0 = fb[4 * Kk], er1 = fb[5 * Kk], er2 = fb[6 * Kk], er3 = fb[7 * Kk];

    const f32x4 zz = {0.f, 0.f, 0.f, 0.f};
    int ktot = 0;
    int kq0 = 0, kq1 = 0, kemb = 0;  // k in fr(t), fr(t+2), next write fr(t+4)
    float probeA, probeB;

#define MFMA16(Aa, Bx, Cc) __builtin_amdgcn_mfma_f32_16x16x32_bf16(Aa, Bx, Cc, 0, 0, 0)

    // unchained: 8 independent MFMAs, pairwise add, scale, pack
#define STEP(F0_, F1_, F2_, F3_, PR) {                                        \
    f32x4 d0a = MFMA16(A00, B0, zz); f32x4 d0b = MFMA16(A01, B1, zz);         \
    f32x4 d1a = MFMA16(A10, B0, zz); f32x4 d1b = MFMA16(A11, B1, zz);         \
    f32x4 d2a = MFMA16(A20, B0, zz); f32x4 d2b = MFMA16(A21, B1, zz);         \
    f32x4 d3a = MFMA16(A30, B0, zz); f32x4 d3b = MFMA16(A31, B1, zz);         \
    f32x4 m0 = (d0a + d0b) * F0_;                                             \
    f32x4 m1 = (d1a + d1b) * F1_;                                             \
    f32x4 m2 = (d2a + d2b) * F2_;                                             \
    f32x4 m3 = (d3a + d3b) * F3_;                                             \
    PR = m0[0];                                                               \
    union { unsigned u[4]; bf16x8 v; } nb0, nb1;                              \
    nb0.u[0] = cvtpk(m0[0], m0[1]); nb0.u[1] = cvtpk(m0[2], m0[3]);           \
    nb0.u[2] = cvtpk(m1[0], m1[1]); nb0.u[3] = cvtpk(m1[2], m1[3]);           \
    nb1.u[0] = cvtpk(m2[0], m2[1]); nb1.u[1] = cvtpk(m2[2], m2[3]);           \
    nb1.u[2] = cvtpk(m3[0], m3[1]); nb1.u[3] = cvtpk(m3[2], m3[3]);           \
    B0 = nb0.v; B1 = nb1.v; }

    int t = 0;
#pragma unroll 2
    for (; t + 1 < len; t += 2) {
        // next iteration's F: fr(t+2) in bank (t+2)&3, fr(t+3) in (t+3)&3.
        // No aliasing with this iteration's writes (banks t&3, (t+1)&3) ->
        // no fences needed; compiler schedules freely around the MFMAs.
        const float* rb0 = &frl[(t + 2) & 3][4 * g];
        const float* rb1 = &frl[(t + 3) & 3][4 * g];
        f32x4 NA0 = *(const f32x4*)(rb0);      f32x4 NA1 = *(const f32x4*)(rb0 + 16);
        f32x4 NA2 = *(const f32x4*)(rb0 + 32); f32x4 NA3 = *(const f32x4*)(rb0 + 48);
        f32x4 NB0 = *(const f32x4*)(rb1);      f32x4 NB1 = *(const f32x4*)(rb1 + 16);
        f32x4 NB2 = *(const f32x4*)(rb1 + 32); f32x4 NB3 = *(const f32x4*)(rb1 + 48);
        const float frA = __builtin_amdgcn_exp2f(fmaf(er0, LOG2E, -(float)kemb));
        const float frB = __builtin_amdgcn_exp2f(er1 * LOG2E);

        STEP(FA0, FA1, FA2, FA3, probeA)
        STEP(FB0, FB1, FB2, FB3, probeB)

        frl[t & 3][l]       = frA;   // fr(t+4), embeds kemb; read at iter t+2
        frl[(t + 1) & 3][l] = frB;   // fr(t+5)

        // ---- bookkeeping (off the MFMA chain) ----
        ktot += kq0;
        const unsigned pb =
            (unsigned)__builtin_amdgcn_readfirstlane(__float_as_int(probeB));
        int knew = ((int)((pb >> 23) & 255) - 127) - kq1 - kemb;  // minus in-flight
        knew = (knew > 100) ? 100 : ((knew < -100) ? -100 : knew);
        kq0 = kq1; kq1 = kemb; kemb = knew;
        FA0 = NA0; FA1 = NA1; FA2 = NA2; FA3 = NA3;   // register renames
        FB0 = NB0; FB1 = NB1; FB2 = NB2; FB3 = NB3;
        er0 = er2; er1 = er3;
        const int r0 = (t + 8 < Tt) ? t + 8 : Tt - 1;
        const int r1 = (t + 9 < Tt) ? t + 9 : Tt - 1;
        er2 = fb[r0 * Kk]; er3 = fb[r1 * Kk];
        (void)probeA;
    }

    // tail (len odd): one step with FA = F(t)
    if (t < len) {
        STEP(FA0, FA1, FA2, FA3, probeA)
        ktot += kq0;
        (void)probeA;
    }

    // terminal: d4 row0 = etstop . alpha (current scale 2^-ktot)
    f32x4 d4 = MFMA16(S0, B0, zz);
    f32x4 d5 = MFMA16(S1, B1, zz);
    d4 = d4 + d5;
    const float term = __uint_as_float(
        (unsigned)__builtin_amdgcn_readfirstlane(__float_as_int(d4[0])));
    if (l == 0) fwd_out[b] = (float)ktot * LN2F + logf(term);
#undef STEP
#undef MFMA16
}

// Gold path score: fully parallel over t (lane-strided).
__global__ __launch_bounds__(64) void crf_gold_kernel(
    const float* __restrict__ feats,
    const float* __restrict__ transitions,
    const int* __restrict__ tags,     // (B,T)
    const int* __restrict__ lengths,  // (B,)
    float* __restrict__ gold_out)     // (B,)
{
    const int b = blockIdx.x;
    const int lane = threadIdx.x;
    const int len = lengths[b];
    const int* tb = tags + b * Tt;
    const float* fb = feats + (size_t)b * Tt * Kk;

    float acc = 0.f;
    for (int t = lane; t < len; t += 64) {
        const int tg = tb[t];
        const int prev = (t == 0) ? START_TAG : tb[t - 1];
        acc += transitions[tg * Kk + prev];  // score prev -> tg
        acc += fb[t * Kk + tg];              // emission
    }
    if (lane == 0) acc += transitions[STOP_TAG * Kk + tb[len - 1]];  // last -> STOP
#pragma unroll
    for (int off = 32; off >= 1; off >>= 1) acc += __shfl_xor(acc, off, 64);
    if (lane == 0) gold_out[b] = acc;
}

__global__ __launch_bounds__(512) void crf_reduce_kernel(
    const float* __restrict__ fwd, const float* __restrict__ gold,
    float* __restrict__ out)
{
    const int i = threadIdx.x;  // 0..511
    float v = fwd[i] - gold[i];
#pragma unroll
    for (int off = 32; off >= 1; off >>= 1) v += __shfl_xor(v, off, 64);
    __shared__ float ws[8];
    if ((i & 63) == 0) ws[i >> 6] = v;
    __syncthreads();
    if (i < 8) {
        float s = ws[i];
#pragma unroll
        for (int off = 4; off >= 1; off >>= 1) s += __shfl_xor(s, off, 8);
        if (i == 0) out[0] = s * (1.0f / (float)Bb);
    }
}

extern "C" void kernel_launch(void* const* d_in, const int* in_sizes, int n_in,
                              void* d_out, int out_size, void* d_ws, size_t ws_size,
                              hipStream_t stream) {
    const float* feats = (const float*)d_in[0];
    const float* trans = (const float*)d_in[1];
    const int* tags = (const int*)d_in[2];
    const int* lengths = (const int*)d_in[3];
    float* out = (float*)d_out;
    float* fwd = (float*)d_ws;
    float* gold = fwd + Bb;

    crf_gold_kernel<<<Bb, 64, 0, stream>>>(feats, trans, tags, lengths, gold);
    crf_forward_mfma<<<Bb, 64, 0, stream>>>(feats, trans, lengths, fwd);
    crf_reduce_kernel<<<1, 512, 0, stream>>>(fwd, gold, out);
}

// Round 10
// 110.093 us; speedup vs baseline: 1.0777x; 1.0777x over previous
//
#include <hip/hip_runtime.h>
#include <hip/hip_bf16.h>

#define Bb 512
#define Tt 512
#define Kk 64
#define START_TAG 62
#define STOP_TAG 63
#define LN2F 0.69314718055994530942f
#define LOG2E 1.44269504088896340736f

typedef __attribute__((ext_vector_type(8))) short bf16x8;  // 8 bf16 in 4 VGPRs
typedef __attribute__((ext_vector_type(4))) float f32x4;   // MFMA C/D
typedef __attribute__((ext_vector_type(2))) float f32x2;   // packed-f32 pair

__device__ inline short f2bf(float x) {
    __hip_bfloat16 h = __float2bfloat16(x);
    short s; __builtin_memcpy(&s, &h, 2); return s;
}
// pack 2 f32 -> 2 bf16 in one instruction
__device__ inline unsigned cvtpk(float lo, float hi) {
    unsigned r;
    asm("v_cvt_pk_bf16_f32 %0, %1, %2" : "=v"(r) : "v"(lo), "v"(hi));
    return r;
}
// packed f32 multiply: one instruction for 2 lansewise f32 muls (CDNA2+)
__device__ inline f32x2 pkmul(f32x2 a, f32x2 b) {
    f32x2 d;
    asm("v_pk_mul_f32 %0, %1, %2" : "=v"(d) : "v"(a), "v"(b));
    return d;
}

// One sequence per 64-lane wave; alpha recursion as MFMA matvec in exp-space.
// Layout (HW-verified r4-r9, absmax 0.0): tag tau(c,r)=32c+16*(r>=4)+4g+(r&3)
// on both A and B sides; D tile i reg r = tag 16i+4g+r -> D feeds next B with
// register moves only.
// Round-10: r8 skeleton (chained SrcC MFMA pairs -- r9 proved unchaining
// REGRESSES ~20%) + two surgical shaves:
//  * v_pk_mul_f32 for the F multiply: 16 v_mul -> 8 packed (issue + chain).
//  * 4-bank rotating LDS frl[4][64], NO fence in the loop (r9's good idea,
//    now isolated from its unchaining confound): reads (banks (t+2)&3,
//    (t+3)&3) never alias writes (banks t&3,(t+1)&3); same-wave DS FIFO
//    carries the rest.
// Rescale queue (kq0/kq1/kemb in-flight accounting, r7-validated) unchanged.
__global__ __launch_bounds__(64, 1) void crf_forward_mfma(
    const float* __restrict__ feats,        // (B,T,K)
    const float* __restrict__ transitions,  // (K,K), trans[i,j] = score j->i
    const int* __restrict__ lengths,        // (B,)
    float* __restrict__ fwd_out)            // (B,)
{
    const int b   = blockIdx.x;
    const int l   = threadIdx.x;
    const int row = l & 15;   // A row / D col
    const int g   = l >> 4;   // k-group

    // fr banks: fr(s) lives in bank s&3, natural layout (lane = tag).
    __shared__ __align__(16) float frl[4][Kk];

    // A fragments: A[i][c] slot r = exp(trans[16i+row][tau(c,r)])
    bf16x8 A00, A01, A10, A11, A20, A21, A30, A31, S0, S1;
#define MKA(Av, i, c) {                                                       \
    const float* p = transitions + (16*(i)+row)*Kk + 32*(c) + 4*g;            \
    float4 lo = *(const float4*)p; float4 hi = *(const float4*)(p + 16);      \
    Av[0]=f2bf(__expf(lo.x)); Av[1]=f2bf(__expf(lo.y));                       \
    Av[2]=f2bf(__expf(lo.z)); Av[3]=f2bf(__expf(lo.w));                       \
    Av[4]=f2bf(__expf(hi.x)); Av[5]=f2bf(__expf(hi.y));                       \
    Av[6]=f2bf(__expf(hi.z)); Av[7]=f2bf(__expf(hi.w)); }
    MKA(A00,0,0) MKA(A01,0,1) MKA(A10,1,0) MKA(A11,1,1)
    MKA(A20,2,0) MKA(A21,2,1) MKA(A30,3,0) MKA(A31,3,1)
#undef MKA
    // Terminal fragments: row 0 = exp(trans[STOP][tau]), rows 1..15 = 0
#define MKS(Av, c) {                                                          \
    const float* p = transitions + STOP_TAG*Kk + 32*(c) + 4*g;                \
    float4 lo = *(const float4*)p; float4 hi = *(const float4*)(p + 16);      \
    const bool z = (row == 0);                                                \
    Av[0]=z?f2bf(__expf(lo.x)):(short)0; Av[1]=z?f2bf(__expf(lo.y)):(short)0; \
    Av[2]=z?f2bf(__expf(lo.z)):(short)0; Av[3]=z?f2bf(__expf(lo.w)):(short)0; \
    Av[4]=z?f2bf(__expf(hi.x)):(short)0; Av[5]=z?f2bf(__expf(hi.y)):(short)0; \
    Av[6]=z?f2bf(__expf(hi.z)):(short)0; Av[7]=z?f2bf(__expf(hi.w)):(short)0; }
    MKS(S0,0) MKS(S1,1)
#undef MKS

    const int len = lengths[b];
    const float* fb = feats + (size_t)b * Tt * Kk + l;  // natural: lane = tag

    // alpha0: 1 at START=62 -> B1 slot 6, g=3
    bf16x8 B0 = {}; bf16x8 B1 = {};
    if (g == 3) B1[6] = (short)0x3F80;  // bf16(1.0)

    // ---- prologue: banks 0..3 = fr(0..3); FA=F(0), FB=F(1) ----
    frl[0][l] = __builtin_amdgcn_exp2f(fb[0]      * LOG2E);
    frl[1][l] = __builtin_amdgcn_exp2f(fb[Kk]     * LOG2E);
    frl[2][l] = __builtin_amdgcn_exp2f(fb[2 * Kk] * LOG2E);
    frl[3][l] = __builtin_amdgcn_exp2f(fb[3 * Kk] * LOG2E);
    __builtin_amdgcn_wave_barrier();   // prologue only; loop has no fences
    f32x2 FA[8], FB[8];
    {
        const f32x2* p0 = (const f32x2*)&frl[0][4 * g];
        const f32x2* p1 = (const f32x2*)&frl[1][4 * g];
#pragma unroll
        for (int q = 0; q < 4; ++q) {
            FA[2*q]   = p0[8*q];   FA[2*q+1] = p0[8*q+1];
            FB[2*q]   = p1[8*q];   FB[2*q+1] = p1[8*q+1];
        }
    }

    // emit ring, 4 deep: er0..er3 = rows t+4..t+7 (rows always allocated)
    float er0 = fb[4 * Kk], er1 = fb[5 * Kk], er2 = fb[6 * Kk], er3 = fb[7 * Kk];

    const f32x4 zz = {0.f, 0.f, 0.f, 0.f};
    int ktot = 0;
    int kq0 = 0, kq1 = 0, kemb = 0;  // k in fr(t), fr(t+2), next write fr(t+4)
    float probeA, probeB;

#define MFMA16(Aa, Bx, Cc) __builtin_amdgcn_mfma_f32_16x16x32_bf16(Aa, Bx, Cc, 0, 0, 0)

    // chained pairs (r8, best) + packed F multiply
#define STEP(FF, PR) {                                                        \
    f32x4 d0 = MFMA16(A00, B0, zz); d0 = MFMA16(A01, B1, d0);                 \
    f32x4 d1 = MFMA16(A10, B0, zz); d1 = MFMA16(A11, B1, d1);                 \
    f32x4 d2 = MFMA16(A20, B0, zz); d2 = MFMA16(A21, B1, d2);                 \
    f32x4 d3 = MFMA16(A30, B0, zz); d3 = MFMA16(A31, B1, d3);                 \
    f32x2 m0a = pkmul(((f32x2){d0[0], d0[1]}), FF[0]);                        \
    f32x2 m0b = pkmul(((f32x2){d0[2], d0[3]}), FF[1]);                        \
    f32x2 m1a = pkmul(((f32x2){d1[0], d1[1]}), FF[2]);                        \
    f32x2 m1b = pkmul(((f32x2){d1[2], d1[3]}), FF[3]);                        \
    f32x2 m2a = pkmul(((f32x2){d2[0], d2[1]}), FF[4]);                        \
    f32x2 m2b = pkmul(((f32x2){d2[2], d2[3]}), FF[5]);                        \
    f32x2 m3a = pkmul(((f32x2){d3[0], d3[1]}), FF[6]);                        \
    f32x2 m3b = pkmul(((f32x2){d3[2], d3[3]}), FF[7]);                        \
    PR = m0a[0];                                                              \
    union { unsigned u[4]; bf16x8 v; } nb0, nb1;                              \
    nb0.u[0] = cvtpk(m0a[0], m0a[1]); nb0.u[1] = cvtpk(m0b[0], m0b[1]);       \
    nb0.u[2] = cvtpk(m1a[0], m1a[1]); nb0.u[3] = cvtpk(m1b[0], m1b[1]);       \
    nb1.u[0] = cvtpk(m2a[0], m2a[1]); nb1.u[1] = cvtpk(m2b[0], m2b[1]);       \
    nb1.u[2] = cvtpk(m3a[0], m3a[1]); nb1.u[3] = cvtpk(m3b[0], m3b[1]);       \
    B0 = nb0.v; B1 = nb1.v; }

    int t = 0;
    for (; t + 1 < len; t += 2) {
        // next iteration's F: fr(t+2) bank (t+2)&3, fr(t+3) bank (t+3)&3.
        // Never aliases this iteration's writes (banks t&3, (t+1)&3):
        // no fences; compiler schedules these into the MFMA windows.
        const f32x2* rb0 = (const f32x2*)&frl[(t + 2) & 3][4 * g];
        const f32x2* rb1 = (const f32x2*)&frl[(t + 3) & 3][4 * g];
        f32x2 NA[8], NB[8];
#pragma unroll
        for (int q = 0; q < 4; ++q) {
            NA[2*q] = rb0[8*q]; NA[2*q+1] = rb0[8*q+1];
            NB[2*q] = rb1[8*q]; NB[2*q+1] = rb1[8*q+1];
        }
        const float frA = __builtin_amdgcn_exp2f(fmaf(er0, LOG2E, -(float)kemb));
        const float frB = __builtin_amdgcn_exp2f(er1 * LOG2E);

        STEP(FA, probeA)
        STEP(FB, probeB)

        frl[t & 3][l]       = frA;   // fr(t+4), embeds kemb; read at iter t+2
        frl[(t + 1) & 3][l] = frB;   // fr(t+5)

        // ---- bookkeeping (off the MFMA chain) ----
        ktot += kq0;
        const unsigned pb =
            (unsigned)__builtin_amdgcn_readfirstlane(__float_as_int(probeB));
        int knew = ((int)((pb >> 23) & 255) - 127) - kq1 - kemb;  // minus in-flight
        knew = (knew > 100) ? 100 : ((knew < -100) ? -100 : knew);
        kq0 = kq1; kq1 = kemb; kemb = knew;
#pragma unroll
        for (int q = 0; q < 8; ++q) { FA[q] = NA[q]; FB[q] = NB[q]; }
        er0 = er2; er1 = er3;
        const int r0 = (t + 8 < Tt) ? t + 8 : Tt - 1;
        const int r1 = (t + 9 < Tt) ? t + 9 : Tt - 1;
        er2 = fb[r0 * Kk]; er3 = fb[r1 * Kk];
        (void)probeA;
    }

    // tail (len odd): one step with FA = F(t)
    if (t < len) {
        STEP(FA, probeA)
        ktot += kq0;
        (void)probeA;
    }

    // terminal: d4 row0 = etstop . alpha (current scale 2^-ktot)
    f32x4 d4 = MFMA16(S0, B0, zz); d4 = MFMA16(S1, B1, d4);
    const float term = __uint_as_float(
        (unsigned)__builtin_amdgcn_readfirstlane(__float_as_int(d4[0])));
    if (l == 0) fwd_out[b] = (float)ktot * LN2F + logf(term);
#undef STEP
#undef MFMA16
}

// Gold path score: fully parallel over t (lane-strided).
__global__ __launch_bounds__(64) void crf_gold_kernel(
    const float* __restrict__ feats,
    const float* __restrict__ transitions,
    const int* __restrict__ tags,     // (B,T)
    const int* __restrict__ lengths,  // (B,)
    float* __restrict__ gold_out)     // (B,)
{
    const int b = blockIdx.x;
    const int lane = threadIdx.x;
    const int len = lengths[b];
    const int* tb = tags + b * Tt;
    const float* fb = feats + (size_t)b * Tt * Kk;

    float acc = 0.f;
    for (int t = lane; t < len; t += 64) {
        const int tg = tb[t];
        const int prev = (t == 0) ? START_TAG : tb[t - 1];
        acc += transitions[tg * Kk + prev];  // score prev -> tg
        acc += fb[t * Kk + tg];              // emission
    }
    if (lane == 0) acc += transitions[STOP_TAG * Kk + tb[len - 1]];  // last -> STOP
#pragma unroll
    for (int off = 32; off >= 1; off >>= 1) acc += __shfl_xor(acc, off, 64);
    if (lane == 0) gold_out[b] = acc;
}

__global__ __launch_bounds__(512) void crf_reduce_kernel(
    const float* __restrict__ fwd, const float* __restrict__ gold,
    float* __restrict__ out)
{
    const int i = threadIdx.x;  // 0..511
    float v = fwd[i] - gold[i];
#pragma unroll
    for (int off = 32; off >= 1; off >>= 1) v += __shfl_xor(v, off, 64);
    __shared__ float ws[8];
    if ((i & 63) == 0) ws[i >> 6] = v;
    __syncthreads();
    if (i < 8) {
        float s = ws[i];
#pragma unroll
        for (int off = 4; off >= 1; off >>= 1) s += __shfl_xor(s, off, 8);
        if (i == 0) out[0] = s * (1.0f / (float)Bb);
    }
}

extern "C" void kernel_launch(void* const* d_in, const int* in_sizes, int n_in,
                              void* d_out, int out_size, void* d_ws, size_t ws_size,
                              hipStream_t stream) {
    const float* feats = (const float*)d_in[0];
    const float* trans = (const float*)d_in[1];
    const int* tags = (const int*)d_in[2];
    const int* lengths = (const int*)d_in[3];
    float* out = (float*)d_out;
    float* fwd = (float*)d_ws;
    float* gold = fwd + Bb;

    crf_gold_kernel<<<Bb, 64, 0, stream>>>(feats, trans, tags, lengths, gold);
    crf_forward_mfma<<<Bb, 64, 0, stream>>>(feats, trans, lengths, fwd);
    crf_reduce_kernel<<<1, 512, 0, stream>>>(fwd, gold, out);
}